// Round 7
// baseline (172.718 us; speedup 1.0000x reference)
//
#include <hip/hip_runtime.h>
#include <hip/hip_bf16.h>

#define NB 16
#define NCH 64
#define NT 2048
#define PSTR 66             // P/merge row stride (shorts): 132 B rows -> low-conflict b128

typedef __attribute__((ext_vector_type(8))) short bf8;
typedef __attribute__((ext_vector_type(4))) short bf4;
typedef __attribute__((ext_vector_type(4))) float f4;

#if defined(__has_builtin)
#if __has_builtin(__builtin_amdgcn_exp2f)
#define EXP2(x) __builtin_amdgcn_exp2f(x)
#else
#define EXP2(x) __expf((x) * 0.69314718056f)
#endif
#else
#define EXP2(x) __expf((x) * 0.69314718056f)
#endif

static __device__ __forceinline__ short f2b(float f) {
    unsigned u = __float_as_uint(f);
    u += 0x7fffu + ((u >> 16) & 1u);
    return (short)(u >> 16);
}
static __device__ __forceinline__ float b2f(short s) {
    return __uint_as_float(((unsigned)(unsigned short)s) << 16);
}

// ---- prep: Xs[b][t] = sum_c x ; xT[b][t][c] bf16 ; xn[b][c][t] bf16 ----
__global__ __launch_bounds__(256)
void prep_k(const float* __restrict__ x, float* __restrict__ Xs,
            short* __restrict__ xT, short* __restrict__ xn) {
    __shared__ float T[NCH][65];
    const int b = blockIdx.y, t0 = blockIdx.x * 64;
    const int tid = threadIdx.x;
    const float* xb = x + (size_t)b * NCH * NT;

    const int tt = (tid & 15) * 4;
    #pragma unroll
    for (int co = 0; co < 4; ++co) {
        int c = co * 16 + (tid >> 4);
        float4 v = *reinterpret_cast<const float4*>(&xb[(size_t)c * NT + t0 + tt]);
        T[c][tt] = v.x; T[c][tt + 1] = v.y; T[c][tt + 2] = v.z; T[c][tt + 3] = v.w;
        bf4 w; w[0] = f2b(v.x); w[1] = f2b(v.y); w[2] = f2b(v.z); w[3] = f2b(v.w);
        *reinterpret_cast<bf4*>(&xn[((size_t)b * NCH + c) * NT + t0 + tt]) = w;
    }
    __syncthreads();
    if (tid < 64) {
        float s = 0.f;
        #pragma unroll
        for (int c = 0; c < NCH; ++c) s += T[c][tid];
        Xs[b * NT + t0 + tid] = s;
    }
    const int row = tid >> 2, cs = (tid & 3) * 16;
    bf8 v0, v1;
    #pragma unroll
    for (int u = 0; u < 8; ++u) v0[u] = f2b(T[cs + u][row]);
    #pragma unroll
    for (int u = 0; u < 8; ++u) v1[u] = f2b(T[cs + 8 + u][row]);
    short* dst = xT + ((size_t)b * NT + t0 + row) * NCH + cs;
    *reinterpret_cast<bf8*>(dst) = v0;
    *reinterpret_cast<bf8*>(dst + 8) = v1;
}

// ---- minmax: 512 thr, 8 waves x 256-j each, 32 i-rows/block; writes final rowMin/Max ----
// f = s11*G + s2b1*Xj (row-constant terms cancel in minmax-norm)
__global__ __launch_bounds__(512)
void minmax_k(const float* __restrict__ w1, const float* __restrict__ b1p,
              const float* __restrict__ w2,
              const float* __restrict__ Xs, const short* __restrict__ xT,
              float* __restrict__ rowMin, float* __restrict__ rowMax) {
    __shared__ float mergeMn[8][2][16];
    __shared__ float mergeMx[8][2][16];

    const int b  = blockIdx.y;
    const int i0 = blockIdx.x * 32;
    const int tid  = threadIdx.x;
    const int w    = tid >> 6;      // wave: j-eighth
    const int lane = tid & 63;
    const int lq = lane >> 4, ln = lane & 15;

    float s11 = 0.f, s2b1 = 0.f;
    #pragma unroll
    for (int f = 0; f < 8; ++f) {
        s11  += w1[f] * w2[f];
        s2b1 += b1p[f] * w2[f];
    }

    const short* xTb = xT + (size_t)b * NT * NCH;

    bf8 Bg[2][2];
    #pragma unroll
    for (int s = 0; s < 2; ++s)
        #pragma unroll
        for (int kk = 0; kk < 2; ++kk)
            Bg[s][kk] = *reinterpret_cast<const bf8*>(
                xTb + (size_t)(i0 + s * 16 + ln) * NCH + kk * 32 + lq * 8);

    float rmin[2] = {3.0e38f, 3.0e38f}, rmax[2] = {-3.0e38f, -3.0e38f};

    for (int t = 0; t < 4; ++t) {
        const int j0t = w * 256 + t * 64;
        const short* abase = xTb + (size_t)j0t * NCH;
        #pragma unroll
        for (int jn = 0; jn < 4; ++jn) {
            float4 xv = *reinterpret_cast<const float4*>(Xs + b * NT + j0t + jn * 16 + lq * 4);
            float t1[4] = { s2b1 * xv.x, s2b1 * xv.y, s2b1 * xv.z, s2b1 * xv.w };
            const short* ap = abase + (size_t)(jn * 16 + ln) * NCH + lq * 8;
            bf8 a0 = *reinterpret_cast<const bf8*>(ap);
            bf8 a1 = *reinterpret_cast<const bf8*>(ap + 32);
            #pragma unroll
            for (int s = 0; s < 2; ++s) {
                f4 acc = {0.f, 0.f, 0.f, 0.f};
                acc = __builtin_amdgcn_mfma_f32_16x16x32_bf16(a0, Bg[s][0], acc, 0, 0, 0);
                acc = __builtin_amdgcn_mfma_f32_16x16x32_bf16(a1, Bg[s][1], acc, 0, 0, 0);
                float e0 = fmaf(s11, acc[0], t1[0]);
                float e1 = fmaf(s11, acc[1], t1[1]);
                float e2 = fmaf(s11, acc[2], t1[2]);
                float e3 = fmaf(s11, acc[3], t1[3]);
                rmin[s] = fminf(rmin[s], fminf(fminf(e0, e1), fminf(e2, e3)));
                rmax[s] = fmaxf(rmax[s], fmaxf(fmaxf(e0, e1), fmaxf(e2, e3)));
            }
        }
    }

    #pragma unroll
    for (int s = 0; s < 2; ++s) {
        rmin[s] = fminf(rmin[s], __shfl_xor(rmin[s], 16, 64));
        rmin[s] = fminf(rmin[s], __shfl_xor(rmin[s], 32, 64));
        rmax[s] = fmaxf(rmax[s], __shfl_xor(rmax[s], 16, 64));
        rmax[s] = fmaxf(rmax[s], __shfl_xor(rmax[s], 32, 64));
    }
    if (lane < 16) {
        #pragma unroll
        for (int s = 0; s < 2; ++s) {
            mergeMn[w][s][ln] = rmin[s];
            mergeMx[w][s][ln] = rmax[s];
        }
    }
    __syncthreads();
    if (tid < 32) {
        float a = mergeMn[0][tid >> 4][tid & 15];
        #pragma unroll
        for (int u = 1; u < 8; ++u) a = fminf(a, mergeMn[u][tid >> 4][tid & 15]);
        rowMin[b * NT + i0 + tid] = a;
    } else if (tid < 64) {
        const int ii = tid - 32;
        float a = mergeMx[0][ii >> 4][ii & 15];
        #pragma unroll
        for (int u = 1; u < 8; ++u) a = fmaxf(a, mergeMx[u][ii >> 4][ii & 15]);
        rowMax[b * NT + i0 + ii] = a;
    }
}

// ---- mixed: 256 thr, 4 waves x 512-j quarters, 16 i-rows/block (grid 2048) ----
__global__ __launch_bounds__(256)
void mixed_k(const float* __restrict__ w1, const float* __restrict__ b1p,
             const float* __restrict__ w2, const float* __restrict__ gp,
             const float* __restrict__ Xs, const short* __restrict__ xT,
             const short* __restrict__ xn, const float* __restrict__ x,
             const float* __restrict__ rowMin, const float* __restrict__ rowMax,
             float* __restrict__ out) {
    // pool: per-wave P scratch [16][PSTR] shorts x4 = 8448 B, overlaid by mergeAcc [4][16][PSTR]
    __shared__ short pool[4 * 16 * PSTR];
    __shared__ float mergePS[4][16];

    const int b  = blockIdx.y;
    const int i0 = blockIdx.x * 16;
    const int tid  = threadIdx.x;
    const int h    = tid >> 6;      // wave: j-quarter
    const int lane = tid & 63;
    const int lq = lane >> 4, ln = lane & 15;

    short* Pw = pool + h * 16 * PSTR;
    short* mergeAcc = pool;         // [w][i(16)][c(64) @ stride PSTR] bf16

    float s11 = 0.f, s2b1 = 0.f;
    #pragma unroll
    for (int f = 0; f < 8; ++f) {
        s11  += w1[f] * w2[f];
        s2b1 += b1p[f] * w2[f];
    }
    const float g = gp[0];

    const short* xTb = xT + (size_t)b * NT * NCH;
    const short* xnb = xn + (size_t)b * NCH * NT;
    const float* xb  = x + (size_t)b * NCH * NT;

    bf8 Bg[2];
    #pragma unroll
    for (int kk = 0; kk < 2; ++kk)
        Bg[kk] = *reinterpret_cast<const bf8*>(
            xTb + (size_t)(i0 + ln) * NCH + kk * 32 + lq * 8);

    // per-row (i = i0+ln) affine: p = exp2(A*acc + t1*inv2 + KI)
    const float mnv = rowMin[b * NT + i0 + ln];
    const float mxv = rowMax[b * NT + i0 + ln];
    const float inv2 = 1.44269504f / (mxv - mnv + 1e-8f);
    const float A  = s11 * inv2;
    const float KI = -mnv * inv2;

    f4 macc[4];
    #pragma unroll
    for (int cb = 0; cb < 4; ++cb) macc[cb] = (f4){0.f, 0.f, 0.f, 0.f};
    float ps = 0.f;

    for (int t = 0; t < 8; ++t) {
        const int j0t = h * 512 + t * 64;
        const short* abase = xTb + (size_t)j0t * NCH;
        #pragma unroll
        for (int jn = 0; jn < 4; ++jn) {
            float4 xv = *reinterpret_cast<const float4*>(Xs + b * NT + j0t + jn * 16 + lq * 4);
            const short* ap = abase + (size_t)(jn * 16 + ln) * NCH + lq * 8;
            bf8 a0 = *reinterpret_cast<const bf8*>(ap);
            bf8 a1 = *reinterpret_cast<const bf8*>(ap + 32);
            f4 acc = {0.f, 0.f, 0.f, 0.f};
            acc = __builtin_amdgcn_mfma_f32_16x16x32_bf16(a0, Bg[0], acc, 0, 0, 0);
            acc = __builtin_amdgcn_mfma_f32_16x16x32_bf16(a1, Bg[1], acc, 0, 0, 0);
            float D0 = fmaf(s2b1 * xv.x, inv2, KI);
            float D1 = fmaf(s2b1 * xv.y, inv2, KI);
            float D2 = fmaf(s2b1 * xv.z, inv2, KI);
            float D3 = fmaf(s2b1 * xv.w, inv2, KI);
            float p0 = EXP2(fmaf(A, acc[0], D0));
            float p1 = EXP2(fmaf(A, acc[1], D1));
            float p2 = EXP2(fmaf(A, acc[2], D2));
            float p3 = EXP2(fmaf(A, acc[3], D3));
            ps += (p0 + p1) + (p2 + p3);
            __hip_bfloat162 q0 = __float22bfloat162_rn(make_float2(p0, p1));
            __hip_bfloat162 q1 = __float22bfloat162_rn(make_float2(p2, p3));
            uint2 uu = make_uint2(*reinterpret_cast<unsigned*>(&q0),
                                  *reinterpret_cast<unsigned*>(&q1));
            *reinterpret_cast<uint2*>(&Pw[ln * PSTR + jn * 16 + lq * 4]) = uu;
        }
        // mixed: macc[c][i=ln] += sum_j xn[c][j] * P[i][j]   (wave-private P)
        bf8 Pf[2];
        #pragma unroll
        for (int kk = 0; kk < 2; ++kk)
            Pf[kk] = *reinterpret_cast<const bf8*>(&Pw[ln * PSTR + kk * 32 + lq * 8]);
        #pragma unroll
        for (int cb = 0; cb < 4; ++cb) {
            const short* mp = xnb + (size_t)(cb * 16 + ln) * NT + j0t + lq * 8;
            bf8 m0 = *reinterpret_cast<const bf8*>(mp);
            bf8 m1 = *reinterpret_cast<const bf8*>(mp + 32);
            macc[cb] = __builtin_amdgcn_mfma_f32_16x16x32_bf16(m0, Pf[0], macc[cb], 0, 0, 0);
            macc[cb] = __builtin_amdgcn_mfma_f32_16x16x32_bf16(m1, Pf[1], macc[cb], 0, 0, 0);
        }
    }

    // row sums over lq then across waves
    ps += __shfl_xor(ps, 16, 64);
    ps += __shfl_xor(ps, 32, 64);
    if (lane < 16) mergePS[h][ln] = ps;
    __syncthreads();   // all waves done with their Pw; mergePS written

    // macc C-layout: col n = ln = i-local, rows = c = cb*16 + lq*4 + r
    #pragma unroll
    for (int cb = 0; cb < 4; ++cb) {
        __hip_bfloat162 q0 = __float22bfloat162_rn(make_float2(macc[cb][0], macc[cb][1]));
        __hip_bfloat162 q1 = __float22bfloat162_rn(make_float2(macc[cb][2], macc[cb][3]));
        uint2 uu = make_uint2(*reinterpret_cast<unsigned*>(&q0),
                              *reinterpret_cast<unsigned*>(&q1));
        *reinterpret_cast<uint2*>(&mergeAcc[(h * 16 + ln) * PSTR + cb * 16 + lq * 4]) = uu;
    }
    __syncthreads();

    float rowSum = mergePS[0][ln] + mergePS[1][ln] + mergePS[2][ln] + mergePS[3][ln];
    const float sc = g / rowSum;

    // thread (h,lq,ln): i = i0+ln, c = h*16 + lq*4 + r
    const int i = i0 + ln;
    #pragma unroll
    for (int r = 0; r < 4; ++r) {
        const int c = h * 16 + lq * 4 + r;
        float tot = 0.f;
        #pragma unroll
        for (int u = 0; u < 4; ++u)
            tot += b2f(mergeAcc[(u * 16 + ln) * PSTR + c]);
        out[((size_t)b * NCH + c) * NT + i] = fmaf(sc, tot, xb[(size_t)c * NT + i]);
    }
}

extern "C" void kernel_launch(void* const* d_in, const int* in_sizes, int n_in,
                              void* d_out, int out_size, void* d_ws, size_t ws_size,
                              hipStream_t stream) {
    const float* x     = (const float*)d_in[0];
    const float* w1    = (const float*)d_in[1];
    const float* b1    = (const float*)d_in[2];
    const float* w2    = (const float*)d_in[3];
    const float* gamma = (const float*)d_in[5];
    float* out = (float*)d_out;

    char* p = (char*)d_ws;
    float* Xs     = (float*)p;            p += (size_t)NB * NT * 4;        // 128 KB
    short* xT     = (short*)p;            p += (size_t)NB * NT * NCH * 2;  // 4 MB
    short* xn     = (short*)p;            p += (size_t)NB * NT * NCH * 2;  // 4 MB
    float* rowMin = (float*)p;            p += (size_t)NB * NT * 4;        // 128 KB
    float* rowMax = (float*)p;                                             // 128 KB

    hipLaunchKernelGGL(prep_k, dim3(NT / 64, NB), dim3(256), 0, stream, x, Xs, xT, xn);
    hipLaunchKernelGGL(minmax_k, dim3(NT / 32, NB), dim3(512), 0, stream,
                       w1, b1, w2, Xs, xT, rowMin, rowMax);
    hipLaunchKernelGGL(mixed_k, dim3(NT / 16, NB), dim3(256), 0, stream,
                       w1, b1, w2, gamma, Xs, xT, xn, x, rowMin, rowMax, out);
}

// Round 8
// 111.590 us; speedup vs baseline: 1.5478x; 1.5478x over previous
//
#include <hip/hip_runtime.h>
#include <hip/hip_bf16.h>

#define NB 16
#define NCH 64
#define NT 2048
#define SPLIT 4
#define JQ (NT / SPLIT)     // 512 j per wave
#define NTILE (JQ / 64)     // 8 tiles of 64
#define PSTR 66             // LDS row stride (shorts): 132 B rows -> low-conflict (r7: 131K)

typedef __attribute__((ext_vector_type(8))) short bf8;
typedef __attribute__((ext_vector_type(4))) short bf4;
typedef __attribute__((ext_vector_type(4))) float f4;

#if defined(__has_builtin)
#if __has_builtin(__builtin_amdgcn_exp2f)
#define EXP2(x) __builtin_amdgcn_exp2f(x)
#else
#define EXP2(x) __expf((x) * 0.69314718056f)
#endif
#else
#define EXP2(x) __expf((x) * 0.69314718056f)
#endif

static __device__ __forceinline__ short f2b(float f) {
    unsigned u = __float_as_uint(f);
    u += 0x7fffu + ((u >> 16) & 1u);
    return (short)(u >> 16);
}
static __device__ __forceinline__ float b2f(short s) {
    return __uint_as_float(((unsigned)(unsigned short)s) << 16);
}

// ---- prep: Xs[b][t] = sum_c x ; xT[b][t][c] bf16 ; xn[b][c][t] bf16 ----
__global__ __launch_bounds__(256)
void prep_k(const float* __restrict__ x, float* __restrict__ Xs,
            short* __restrict__ xT, short* __restrict__ xn) {
    __shared__ float T[NCH][65];
    const int b = blockIdx.y, t0 = blockIdx.x * 64;
    const int tid = threadIdx.x;
    const float* xb = x + (size_t)b * NCH * NT;

    const int tt = (tid & 15) * 4;
    #pragma unroll
    for (int co = 0; co < 4; ++co) {
        int c = co * 16 + (tid >> 4);
        float4 v = *reinterpret_cast<const float4*>(&xb[(size_t)c * NT + t0 + tt]);
        T[c][tt] = v.x; T[c][tt + 1] = v.y; T[c][tt + 2] = v.z; T[c][tt + 3] = v.w;
        bf4 w; w[0] = f2b(v.x); w[1] = f2b(v.y); w[2] = f2b(v.z); w[3] = f2b(v.w);
        *reinterpret_cast<bf4*>(&xn[((size_t)b * NCH + c) * NT + t0 + tt]) = w;
    }
    __syncthreads();
    if (tid < 64) {
        float s = 0.f;
        #pragma unroll
        for (int c = 0; c < NCH; ++c) s += T[c][tid];
        Xs[b * NT + t0 + tid] = s;
    }
    const int row = tid >> 2, cs = (tid & 3) * 16;
    bf8 v0, v1;
    #pragma unroll
    for (int u = 0; u < 8; ++u) v0[u] = f2b(T[cs + u][row]);
    #pragma unroll
    for (int u = 0; u < 8; ++u) v1[u] = f2b(T[cs + 8 + u][row]);
    short* dst = xT + ((size_t)b * NT + t0 + row) * NCH + cs;
    *reinterpret_cast<bf8*>(dst) = v0;
    *reinterpret_cast<bf8*>(dst + 8) = v1;
}

// ---- fused: wave-private streaming + software-pipelined pass 2 ----
__global__ __launch_bounds__(256)
void attn8_k(const float* __restrict__ w1, const float* __restrict__ b1p,
             const float* __restrict__ w2, const float* __restrict__ gp,
             const float* __restrict__ Xs, const short* __restrict__ xT,
             const short* __restrict__ xn, const float* __restrict__ x,
             float* __restrict__ out) {
    // per-wave double-buffered P scratch: 4 waves x 2 bufs x 32 rows x PSTR shorts = 33792 B
    // overlaid after last P read by bf16 mergeAcc [128 rows][PSTR]
    __shared__ short pool[4 * 2 * 32 * PSTR];
    __shared__ float mergeMn[4][2][16];
    __shared__ float mergeMx[4][2][16];
    __shared__ float mergePS[4][2][16];

    const int b  = blockIdx.y;
    const int i0 = blockIdx.x * 32;
    const int tid  = threadIdx.x;
    const int h    = tid >> 6;      // j-quarter owned by this wave
    const int lane = tid & 63;
    const int lq = lane >> 4, ln = lane & 15;

    short* P0 = pool + h * (2 * 32 * PSTR);
    short* P1 = P0 + 32 * PSTR;
    short* mergeAcc = pool;         // [w*32 + i(32)][c @ stride PSTR] bf16

    float s11 = 0.f, s2b1 = 0.f;
    #pragma unroll
    for (int f = 0; f < 8; ++f) {
        s11  += w1[f] * w2[f];
        s2b1 += b1p[f] * w2[f];
    }
    const float g = gp[0];

    const short* xTb = xT + (size_t)b * NT * NCH;
    const short* xnb = xn + (size_t)b * NCH * NT;
    const float* xb  = x + (size_t)b * NCH * NT;

    // constant B-frags (i-side of Gram^T): B[k=c][n=i-local], i = i0 + s*16 + ln
    bf8 Bg[2][2];
    #pragma unroll
    for (int s = 0; s < 2; ++s)
        #pragma unroll
        for (int kk = 0; kk < 2; ++kk)
            Bg[s][kk] = *reinterpret_cast<const bf8*>(
                xTb + (size_t)(i0 + s * 16 + ln) * NCH + kk * 32 + lq * 8);

    float rmin[2] = {3.0e38f, 3.0e38f}, rmax[2] = {-3.0e38f, -3.0e38f};

    // ---------- pass 1: row min/max of f = s11*G + s2b1*Xj (no barriers) ----------
    for (int t = 0; t < NTILE; ++t) {
        const int j0t = h * JQ + t * 64;
        const short* abase = xTb + (size_t)j0t * NCH;
        #pragma unroll
        for (int jn = 0; jn < 4; ++jn) {
            float4 xv = *reinterpret_cast<const float4*>(Xs + b * NT + j0t + jn * 16 + lq * 4);
            float t1[4] = { s2b1 * xv.x, s2b1 * xv.y, s2b1 * xv.z, s2b1 * xv.w };
            const short* ap = abase + (size_t)(jn * 16 + ln) * NCH + lq * 8;
            bf8 a0 = *reinterpret_cast<const bf8*>(ap);
            bf8 a1 = *reinterpret_cast<const bf8*>(ap + 32);
            #pragma unroll
            for (int s = 0; s < 2; ++s) {
                f4 acc = {0.f, 0.f, 0.f, 0.f};
                acc = __builtin_amdgcn_mfma_f32_16x16x32_bf16(a0, Bg[s][0], acc, 0, 0, 0);
                acc = __builtin_amdgcn_mfma_f32_16x16x32_bf16(a1, Bg[s][1], acc, 0, 0, 0);
                float e0 = fmaf(s11, acc[0], t1[0]);
                float e1 = fmaf(s11, acc[1], t1[1]);
                float e2 = fmaf(s11, acc[2], t1[2]);
                float e3 = fmaf(s11, acc[3], t1[3]);
                rmin[s] = fminf(rmin[s], fminf(fminf(e0, e1), fminf(e2, e3)));
                rmax[s] = fmaxf(rmax[s], fmaxf(fmaxf(e0, e1), fmaxf(e2, e3)));
            }
        }
    }

    #pragma unroll
    for (int s = 0; s < 2; ++s) {
        rmin[s] = fminf(rmin[s], __shfl_xor(rmin[s], 16, 64));
        rmin[s] = fminf(rmin[s], __shfl_xor(rmin[s], 32, 64));
        rmax[s] = fmaxf(rmax[s], __shfl_xor(rmax[s], 16, 64));
        rmax[s] = fmaxf(rmax[s], __shfl_xor(rmax[s], 32, 64));
    }
    if (lane < 16) {
        #pragma unroll
        for (int s = 0; s < 2; ++s) {
            mergeMn[h][s][ln] = rmin[s];
            mergeMx[h][s][ln] = rmax[s];
        }
    }
    __syncthreads();

    // per-row affine: p = exp2(A[s]*acc + Xj*s2i[s] + KI[s])
    float A[2], KI[2], s2i[2];
    #pragma unroll
    for (int s = 0; s < 2; ++s) {
        float a = mergeMn[0][s][ln], bb = mergeMx[0][s][ln];
        #pragma unroll
        for (int w = 1; w < 4; ++w) {
            a  = fminf(a, mergeMn[w][s][ln]);
            bb = fmaxf(bb, mergeMx[w][s][ln]);
        }
        const float inv2 = 1.44269504f / (bb - a + 1e-8f);
        A[s]   = s11 * inv2;
        KI[s]  = -a * inv2;
        s2i[s] = s2b1 * inv2;
    }

    f4 macc[4][2];
    #pragma unroll
    for (int cb = 0; cb < 4; ++cb)
        #pragma unroll
        for (int s = 0; s < 2; ++s)
            macc[cb][s] = (f4){0.f, 0.f, 0.f, 0.f};
    float ps[2] = {0.f, 0.f};

    // ---------- pass 2: software-pipelined  gram_exp(t+1) || mixed(t) ----------
    auto gram_exp = [&](int t, short* Pb) {
        const int j0t = h * JQ + t * 64;
        const short* abase = xTb + (size_t)j0t * NCH;
        #pragma unroll
        for (int jn = 0; jn < 4; ++jn) {
            float4 xv = *reinterpret_cast<const float4*>(Xs + b * NT + j0t + jn * 16 + lq * 4);
            const short* ap = abase + (size_t)(jn * 16 + ln) * NCH + lq * 8;
            bf8 a0 = *reinterpret_cast<const bf8*>(ap);
            bf8 a1 = *reinterpret_cast<const bf8*>(ap + 32);
            #pragma unroll
            for (int s = 0; s < 2; ++s) {
                f4 acc = {0.f, 0.f, 0.f, 0.f};
                acc = __builtin_amdgcn_mfma_f32_16x16x32_bf16(a0, Bg[s][0], acc, 0, 0, 0);
                acc = __builtin_amdgcn_mfma_f32_16x16x32_bf16(a1, Bg[s][1], acc, 0, 0, 0);
                float D0 = fmaf(xv.x, s2i[s], KI[s]);
                float D1 = fmaf(xv.y, s2i[s], KI[s]);
                float D2 = fmaf(xv.z, s2i[s], KI[s]);
                float D3 = fmaf(xv.w, s2i[s], KI[s]);
                float p0 = EXP2(fmaf(A[s], acc[0], D0));
                float p1 = EXP2(fmaf(A[s], acc[1], D1));
                float p2 = EXP2(fmaf(A[s], acc[2], D2));
                float p3 = EXP2(fmaf(A[s], acc[3], D3));
                ps[s] += (p0 + p1) + (p2 + p3);
                __hip_bfloat162 q0 = __float22bfloat162_rn(make_float2(p0, p1));
                __hip_bfloat162 q1 = __float22bfloat162_rn(make_float2(p2, p3));
                uint2 uu = make_uint2(*reinterpret_cast<unsigned*>(&q0),
                                      *reinterpret_cast<unsigned*>(&q1));
                *reinterpret_cast<uint2*>(&Pb[(s * 16 + ln) * PSTR + jn * 16 + lq * 4]) = uu;
            }
        }
    };
    auto mixed_st = [&](int t, const short* Pb) {
        const int j0t = h * JQ + t * 64;
        bf8 Pf[2][2];
        #pragma unroll
        for (int s = 0; s < 2; ++s)
            #pragma unroll
            for (int kk = 0; kk < 2; ++kk)
                Pf[s][kk] = *reinterpret_cast<const bf8*>(
                    &Pb[(s * 16 + ln) * PSTR + kk * 32 + lq * 8]);
        #pragma unroll
        for (int cb = 0; cb < 4; ++cb) {
            const short* mp = xnb + (size_t)(cb * 16 + ln) * NT + j0t + lq * 8;
            bf8 m0 = *reinterpret_cast<const bf8*>(mp);
            bf8 m1 = *reinterpret_cast<const bf8*>(mp + 32);
            #pragma unroll
            for (int s = 0; s < 2; ++s) {
                macc[cb][s] = __builtin_amdgcn_mfma_f32_16x16x32_bf16(m0, Pf[s][0], macc[cb][s], 0, 0, 0);
                macc[cb][s] = __builtin_amdgcn_mfma_f32_16x16x32_bf16(m1, Pf[s][1], macc[cb][s], 0, 0, 0);
            }
        }
    };

    gram_exp(0, P0);
    #pragma unroll
    for (int tp = 0; tp < 3; ++tp) {
        gram_exp(2 * tp + 1, P1);
        mixed_st(2 * tp,     P0);
        gram_exp(2 * tp + 2, P0);
        mixed_st(2 * tp + 1, P1);
    }
    gram_exp(7, P1);
    mixed_st(6, P0);
    mixed_st(7, P1);

    // ---------- merge across quarters ----------
    #pragma unroll
    for (int s = 0; s < 2; ++s) {
        ps[s] += __shfl_xor(ps[s], 16, 64);
        ps[s] += __shfl_xor(ps[s], 32, 64);
    }
    if (lane < 16) {
        #pragma unroll
        for (int s = 0; s < 2; ++s) mergePS[h][s][ln] = ps[s];
    }
    __syncthreads();   // all waves done reading P bufs (overlay) + PS written

    #pragma unroll
    for (int cb = 0; cb < 4; ++cb)
        #pragma unroll
        for (int s = 0; s < 2; ++s) {
            __hip_bfloat162 q0 = __float22bfloat162_rn(make_float2(macc[cb][s][0], macc[cb][s][1]));
            __hip_bfloat162 q1 = __float22bfloat162_rn(make_float2(macc[cb][s][2], macc[cb][s][3]));
            uint2 uu = make_uint2(*reinterpret_cast<unsigned*>(&q0),
                                  *reinterpret_cast<unsigned*>(&q1));
            *reinterpret_cast<uint2*>(
                &mergeAcc[(h * 32 + s * 16 + ln) * PSTR + cb * 16 + lq * 4]) = uu;
        }
    __syncthreads();

    float rowSum[2];
    #pragma unroll
    for (int s = 0; s < 2; ++s) {
        float v = 0.f;
        #pragma unroll
        for (int w = 0; w < 4; ++w) v += mergePS[w][s][ln];
        rowSum[s] = v;
    }

    // wave h writes c-range [h*16, h*16+16)
    #pragma unroll
    for (int s = 0; s < 2; ++s) {
        const int i = i0 + s * 16 + ln;
        float tot[4] = {0.f, 0.f, 0.f, 0.f};
        #pragma unroll
        for (int w = 0; w < 4; ++w) {
            bf4 v = *reinterpret_cast<const bf4*>(
                &mergeAcc[(w * 32 + s * 16 + ln) * PSTR + h * 16 + lq * 4]);
            tot[0] += b2f(v[0]); tot[1] += b2f(v[1]);
            tot[2] += b2f(v[2]); tot[3] += b2f(v[3]);
        }
        const float sc = g / rowSum[s];
        #pragma unroll
        for (int r = 0; r < 4; ++r) {
            const int c = h * 16 + lq * 4 + r;
            out[((size_t)b * NCH + c) * NT + i] = fmaf(sc, tot[r], xb[(size_t)c * NT + i]);
        }
    }
}

extern "C" void kernel_launch(void* const* d_in, const int* in_sizes, int n_in,
                              void* d_out, int out_size, void* d_ws, size_t ws_size,
                              hipStream_t stream) {
    const float* x     = (const float*)d_in[0];
    const float* w1    = (const float*)d_in[1];
    const float* b1    = (const float*)d_in[2];
    const float* w2    = (const float*)d_in[3];
    const float* gamma = (const float*)d_in[5];
    float* out = (float*)d_out;

    char* p = (char*)d_ws;
    float* Xs = (float*)p;   p += (size_t)NB * NT * 4;        // 128 KB
    short* xT = (short*)p;   p += (size_t)NB * NT * NCH * 2;  // 4 MB
    short* xn = (short*)p;                                     // 4 MB

    hipLaunchKernelGGL(prep_k, dim3(NT / 64, NB), dim3(256), 0, stream, x, Xs, xT, xn);
    hipLaunchKernelGGL(attn8_k, dim3(NT / 32, NB), dim3(256), 0, stream,
                       w1, b1, w2, gamma, Xs, xT, xn, x, out);
}